// Round 2
// baseline (434.570 us; speedup 1.0000x reference)
//
#include <hip/hip_runtime.h>
#include <cstddef>

// Problem constants
static constexpr int kB    = 256;   // batch
static constexpr int kS    = 196;   // att size (sequence)
static constexpr int kRNN  = 1024;  // rnn size
static constexpr int kATTH = 512;   // att hidden size
static constexpr int kChunks    = 4;    // split-K over s
static constexpr int kSPerChunk = 49;   // 196 / 4

__device__ __forceinline__ float fast_tanh(float x) {
    // tanh(x) = (e^{2x}-1)/(e^{2x}+1); clamp so __expf stays finite.
    x = fminf(12.0f, fmaxf(-12.0f, x));
    float e = __expf(2.0f * x);
    return __fdividef(e - 1.0f, e + 1.0f);
}

// att_h[m,n] = sum_k h[m,k] * w[n,k] + bias[n]
// M=256 (B), N=512 (ATTH), K=1024 (RNN). 32x32 tiles, BK=32, 256 threads.
__global__ __launch_bounds__(256) void gemm_atth(
    const float* __restrict__ h, const float* __restrict__ w,
    const float* __restrict__ bias, float* __restrict__ att_h) {
    __shared__ float As[32][33];
    __shared__ float Bs[32][33];
    const int bm = blockIdx.x * 32;
    const int bn = blockIdx.y * 32;
    const int tid = threadIdx.x;
    const int lrow = tid >> 3;
    const int lcol = (tid & 7) << 2;
    const int tx = tid & 31;
    const int ty = tid >> 5;
    float acc[4] = {0.f, 0.f, 0.f, 0.f};
    for (int k0 = 0; k0 < kRNN; k0 += 32) {
        float4 av = *(const float4*)&h[(size_t)(bm + lrow) * kRNN + k0 + lcol];
        float4 bv = *(const float4*)&w[(size_t)(bn + lrow) * kRNN + k0 + lcol];
        As[lrow][lcol + 0] = av.x; As[lrow][lcol + 1] = av.y;
        As[lrow][lcol + 2] = av.z; As[lrow][lcol + 3] = av.w;
        Bs[lrow][lcol + 0] = bv.x; Bs[lrow][lcol + 1] = bv.y;
        Bs[lrow][lcol + 2] = bv.z; Bs[lrow][lcol + 3] = bv.w;
        __syncthreads();
#pragma unroll
        for (int k = 0; k < 32; ++k) {
            float bb = Bs[tx][k];
#pragma unroll
            for (int i = 0; i < 4; ++i) acc[i] += As[ty * 4 + i][k] * bb;
        }
        __syncthreads();
    }
    const float bval = bias[bn + tx];
#pragma unroll
    for (int i = 0; i < 4; ++i)
        att_h[(size_t)(bm + ty * 4 + i) * kATTH + bn + tx] = acc[i] + bval;
}

// scores[b,s] = sum_a tanh(p_att[b,s,a] + att_h[b,a]) * w_alpha[a]
// (b_alpha omitted: softmax is shift-invariant.)
// Grid: (B, kChunks), 256 threads = 4 waves. Wave handles every 4th row of its
// 49-row chunk; lane holds its 8 att_h/w_alpha elems in registers.
__global__ __launch_bounds__(256) void scores_kernel(
    const float* __restrict__ p_att, const float* __restrict__ att_h,
    const float* __restrict__ w_alpha, float* __restrict__ scores) {
    const int b = blockIdx.x;
    const int c = blockIdx.y;
    const int tid = threadIdx.x;
    const int lane = tid & 63;
    const int wave = tid >> 6;  // 0..3
    const int col = lane << 3;  // 8 floats per lane covers ATTH=512

    const float4 ah0 = *(const float4*)&att_h[(size_t)b * kATTH + col];
    const float4 ah1 = *(const float4*)&att_h[(size_t)b * kATTH + col + 4];
    const float4 wa0 = *(const float4*)&w_alpha[col];
    const float4 wa1 = *(const float4*)&w_alpha[col + 4];

    const int s_end = (c + 1) * kSPerChunk;
    for (int s = c * kSPerChunk + wave; s < s_end; s += 4) {
        const float* p = &p_att[((size_t)b * kS + s) * kATTH + col];
        const float4 p0 = *(const float4*)p;
        const float4 p1 = *(const float4*)(p + 4);
        float r;
        r  = fast_tanh(p0.x + ah0.x) * wa0.x;
        r += fast_tanh(p0.y + ah0.y) * wa0.y;
        r += fast_tanh(p0.z + ah0.z) * wa0.z;
        r += fast_tanh(p0.w + ah0.w) * wa0.w;
        r += fast_tanh(p1.x + ah1.x) * wa1.x;
        r += fast_tanh(p1.y + ah1.y) * wa1.y;
        r += fast_tanh(p1.z + ah1.z) * wa1.z;
        r += fast_tanh(p1.w + ah1.w) * wa1.w;
#pragma unroll
        for (int off = 32; off > 0; off >>= 1) r += __shfl_xor(r, off, 64);
        if (lane == 0) scores[b * kS + s] = r;
    }
}

// partial[b,c,d] = sum_{s in chunk c} softmax(scores[b,:])[s] * att_feats[b,s,d]
// Grid: (B, kChunks), 256 threads. Softmax over 196 scores recomputed
// in-block (cheap: 200 KB total re-read across all blocks).
__global__ __launch_bounds__(256) void wsum_kernel(
    const float* __restrict__ att_feats, const float* __restrict__ scores,
    float* __restrict__ partial) {
    const int b = blockIdx.x;
    const int c = blockIdx.y;
    const int tid = threadIdx.x;
    const int lane = tid & 63;
    const int wave = tid >> 6;  // 0..3

    __shared__ float sW[kS];
    __shared__ float sRed[8];

    // ---- softmax weights into sW
    const float v = (tid < kS) ? scores[b * kS + tid] : -3.0e38f;
    float m = v;
#pragma unroll
    for (int off = 32; off > 0; off >>= 1) m = fmaxf(m, __shfl_xor(m, off, 64));
    if (lane == 0) sRed[wave] = m;
    __syncthreads();
    m = fmaxf(fmaxf(sRed[0], sRed[1]), fmaxf(sRed[2], sRed[3]));
    const float e = (tid < kS) ? __expf(v - m) : 0.f;
    float sum = e;
#pragma unroll
    for (int off = 32; off > 0; off >>= 1) sum += __shfl_xor(sum, off, 64);
    if (lane == 0) sRed[4 + wave] = sum;
    __syncthreads();
    const float tot = sRed[4] + sRed[5] + sRed[6] + sRed[7];
    if (tid < kS) sW[tid] = e * __fdividef(1.0f, tot);
    __syncthreads();

    // ---- weighted partial sum over this block's 49 s-rows
    const int d4 = tid << 2;  // thread covers 4 floats; 256 thr * 4 = 1024 = RNN
    const float* base = &att_feats[((size_t)b * kS + c * kSPerChunk) * kRNN + d4];
    float4 acc = {0.f, 0.f, 0.f, 0.f};
#pragma unroll 7
    for (int i = 0; i < kSPerChunk; ++i) {
        const float w = sW[c * kSPerChunk + i];
        const float4 x = *(const float4*)(base + (size_t)i * kRNN);
        acc.x += w * x.x; acc.y += w * x.y;
        acc.z += w * x.z; acc.w += w * x.w;
    }
    *(float4*)&partial[((size_t)b * kChunks + c) * kRNN + d4] = acc;
}

// out[b,d] = sum_c partial[b,c,d]. Grid: B blocks x 256 threads (float4 each).
__global__ __launch_bounds__(256) void reduce_kernel(
    const float* __restrict__ partial, float* __restrict__ out) {
    const int b = blockIdx.x;
    const int d4 = threadIdx.x << 2;
    const size_t base = (size_t)b * kChunks * kRNN + d4;
    const float4 p0 = *(const float4*)&partial[base];
    const float4 p1 = *(const float4*)&partial[base + kRNN];
    const float4 p2 = *(const float4*)&partial[base + 2 * kRNN];
    const float4 p3 = *(const float4*)&partial[base + 3 * kRNN];
    float4 r;
    r.x = (p0.x + p1.x) + (p2.x + p3.x);
    r.y = (p0.y + p1.y) + (p2.y + p3.y);
    r.z = (p0.z + p1.z) + (p2.z + p3.z);
    r.w = (p0.w + p1.w) + (p2.w + p3.w);
    *(float4*)&out[(size_t)b * kRNN + d4] = r;
}

extern "C" void kernel_launch(void* const* d_in, const int* in_sizes, int n_in,
                              void* d_out, int out_size, void* d_ws, size_t ws_size,
                              hipStream_t stream) {
    const float* h         = (const float*)d_in[0];
    const float* att_feats = (const float*)d_in[1];
    const float* p_att     = (const float*)d_in[2];
    const float* w_h2att   = (const float*)d_in[3];
    const float* b_h2att   = (const float*)d_in[4];
    const float* w_alpha   = (const float*)d_in[5];
    // d_in[6] (b_alpha) is unused: softmax is shift-invariant.
    float* out = (float*)d_out;

    // ws layout: [0, 512K) att_h | [512K, 1M) scores | [1M, 5M) partials
    char* ws = (char*)d_ws;
    float* att_h   = (float*)(ws);                  // 256*512*4  = 512 KB
    float* scores  = (float*)(ws + (512u << 10));   // 256*196*4  = 200 KB
    float* partial = (float*)(ws + (1u << 20));     // 256*4*1024*4 = 4 MB

    dim3 g1(kB / 32, kATTH / 32);  // (8,16)
    gemm_atth<<<g1, 256, 0, stream>>>(h, w_h2att, b_h2att, att_h);

    dim3 g2(kB, kChunks);  // (256,4) = 1024 blocks
    scores_kernel<<<g2, 256, 0, stream>>>(p_att, att_h, w_alpha, scores);
    wsum_kernel<<<g2, 256, 0, stream>>>(att_feats, scores, partial);
    reduce_kernel<<<kB, 256, 0, stream>>>(partial, out);
}

// Round 3
// 432.082 us; speedup vs baseline: 1.0058x; 1.0058x over previous
//
#include <hip/hip_runtime.h>
#include <cstddef>

// Problem constants
static constexpr int kB    = 256;   // batch
static constexpr int kS    = 196;   // att size (sequence)
static constexpr int kRNN  = 1024;  // rnn size
static constexpr int kATTH = 512;   // att hidden size
static constexpr int kChunks    = 4;    // split over s for scores kernel
static constexpr int kSPerChunk = 49;   // 196 / 4

__device__ __forceinline__ float fast_tanh(float x) {
    // tanh(x) = (e^{2x}-1)/(e^{2x}+1); clamp so __expf stays finite.
    x = fminf(12.0f, fmaxf(-12.0f, x));
    float e = __expf(2.0f * x);
    return __fdividef(e - 1.0f, e + 1.0f);
}

// att_h[m,n] = sum_k h[m,k] * w[n,k] + bias[n]
// M=256 (B), N=512 (ATTH), K=1024 (RNN). 32x32 tiles, BK=32, 256 threads.
__global__ __launch_bounds__(256) void gemm_atth(
    const float* __restrict__ h, const float* __restrict__ w,
    const float* __restrict__ bias, float* __restrict__ att_h) {
    __shared__ float As[32][33];
    __shared__ float Bs[32][33];
    const int bm = blockIdx.x * 32;
    const int bn = blockIdx.y * 32;
    const int tid = threadIdx.x;
    const int lrow = tid >> 3;
    const int lcol = (tid & 7) << 2;
    const int tx = tid & 31;
    const int ty = tid >> 5;
    float acc[4] = {0.f, 0.f, 0.f, 0.f};
    for (int k0 = 0; k0 < kRNN; k0 += 32) {
        float4 av = *(const float4*)&h[(size_t)(bm + lrow) * kRNN + k0 + lcol];
        float4 bv = *(const float4*)&w[(size_t)(bn + lrow) * kRNN + k0 + lcol];
        As[lrow][lcol + 0] = av.x; As[lrow][lcol + 1] = av.y;
        As[lrow][lcol + 2] = av.z; As[lrow][lcol + 3] = av.w;
        Bs[lrow][lcol + 0] = bv.x; Bs[lrow][lcol + 1] = bv.y;
        Bs[lrow][lcol + 2] = bv.z; Bs[lrow][lcol + 3] = bv.w;
        __syncthreads();
#pragma unroll
        for (int k = 0; k < 32; ++k) {
            float bb = Bs[tx][k];
#pragma unroll
            for (int i = 0; i < 4; ++i) acc[i] += As[ty * 4 + i][k] * bb;
        }
        __syncthreads();
    }
    const float bval = bias[bn + tx];
#pragma unroll
    for (int i = 0; i < 4; ++i)
        att_h[(size_t)(bm + ty * 4 + i) * kATTH + bn + tx] = acc[i] + bval;
}

// scores[b,s] = sum_a tanh(p_att[b,s,a] + att_h[b,a]) * w_alpha[a]
// (b_alpha omitted: softmax is shift-invariant.)
// Grid: (B, kChunks), 256 threads = 4 waves; ~4 blocks/CU for BW.
__global__ __launch_bounds__(256) void scores_kernel(
    const float* __restrict__ p_att, const float* __restrict__ att_h,
    const float* __restrict__ w_alpha, float* __restrict__ scores) {
    const int b = blockIdx.x;
    const int c = blockIdx.y;
    const int tid = threadIdx.x;
    const int lane = tid & 63;
    const int wave = tid >> 6;  // 0..3
    const int col = lane << 3;  // 8 floats per lane covers ATTH=512

    const float4 ah0 = *(const float4*)&att_h[(size_t)b * kATTH + col];
    const float4 ah1 = *(const float4*)&att_h[(size_t)b * kATTH + col + 4];
    const float4 wa0 = *(const float4*)&w_alpha[col];
    const float4 wa1 = *(const float4*)&w_alpha[col + 4];

    const int s_end = (c + 1) * kSPerChunk;
    for (int s = c * kSPerChunk + wave; s < s_end; s += 4) {
        const float* p = &p_att[((size_t)b * kS + s) * kATTH + col];
        const float4 p0 = *(const float4*)p;
        const float4 p1 = *(const float4*)(p + 4);
        float r;
        r  = fast_tanh(p0.x + ah0.x) * wa0.x;
        r += fast_tanh(p0.y + ah0.y) * wa0.y;
        r += fast_tanh(p0.z + ah0.z) * wa0.z;
        r += fast_tanh(p0.w + ah0.w) * wa0.w;
        r += fast_tanh(p1.x + ah1.x) * wa1.x;
        r += fast_tanh(p1.y + ah1.y) * wa1.y;
        r += fast_tanh(p1.z + ah1.z) * wa1.z;
        r += fast_tanh(p1.w + ah1.w) * wa1.w;
#pragma unroll
        for (int off = 32; off > 0; off >>= 1) r += __shfl_xor(r, off, 64);
        if (lane == 0) scores[b * kS + s] = r;
    }
}

// One block per b: softmax(scores[b,:]) then out[b,d] = sum_s w[s]*att_feats[b,s,d].
// 1024 threads = 16 waves; 4-way s-split in phase C, LDS reduce, direct store.
__global__ __launch_bounds__(1024) void wsum_full(
    const float* __restrict__ att_feats, const float* __restrict__ scores,
    float* __restrict__ out) {
    const int b = blockIdx.x;
    const int tid = threadIdx.x;
    const int lane = tid & 63;
    const int wave = tid >> 6;  // 0..15

    __shared__ float sW[kS];
    __shared__ float sMax[16];
    __shared__ float sSum[16];
    __shared__ float4 sRed[3][256];

    // ---- softmax weights into sW (all 16 waves participate in the reduce)
    const float v = (tid < kS) ? scores[b * kS + tid] : -3.0e38f;
    float m = v;
#pragma unroll
    for (int off = 32; off > 0; off >>= 1) m = fmaxf(m, __shfl_xor(m, off, 64));
    if (lane == 0) sMax[wave] = m;
    __syncthreads();
    m = sMax[0];
#pragma unroll
    for (int i = 1; i < 16; ++i) m = fmaxf(m, sMax[i]);
    const float e = (tid < kS) ? __expf(v - m) : 0.f;
    float sum = e;
#pragma unroll
    for (int off = 32; off > 0; off >>= 1) sum += __shfl_xor(sum, off, 64);
    if (lane == 0) sSum[wave] = sum;
    __syncthreads();
    float tot = sSum[0];
#pragma unroll
    for (int i = 1; i < 16; ++i) tot += sSum[i];
    if (tid < kS) sW[tid] = e * __fdividef(1.0f, tot);
    __syncthreads();

    // ---- weighted sum, float4 per thread, 4-way s-split
    const int d4 = tid & 255;  // float4 index over RNN=1024
    const int sg = tid >> 8;   // 0..3
    float4 acc = {0.f, 0.f, 0.f, 0.f};
    for (int s = sg; s < kS; s += 4) {
        const float ws = sW[s];
        const float4 x =
            *(const float4*)&att_feats[((size_t)b * kS + s) * kRNN + (d4 << 2)];
        acc.x += ws * x.x; acc.y += ws * x.y;
        acc.z += ws * x.z; acc.w += ws * x.w;
    }
    if (sg > 0) sRed[sg - 1][d4] = acc;
    __syncthreads();
    if (sg == 0) {
        const float4 r0 = sRed[0][d4];
        const float4 r1 = sRed[1][d4];
        const float4 r2 = sRed[2][d4];
        acc.x += r0.x + r1.x + r2.x;
        acc.y += r0.y + r1.y + r2.y;
        acc.z += r0.z + r1.z + r2.z;
        acc.w += r0.w + r1.w + r2.w;
        *(float4*)&out[(size_t)b * kRNN + (d4 << 2)] = acc;
    }
}

extern "C" void kernel_launch(void* const* d_in, const int* in_sizes, int n_in,
                              void* d_out, int out_size, void* d_ws, size_t ws_size,
                              hipStream_t stream) {
    const float* h         = (const float*)d_in[0];
    const float* att_feats = (const float*)d_in[1];
    const float* p_att     = (const float*)d_in[2];
    const float* w_h2att   = (const float*)d_in[3];
    const float* b_h2att   = (const float*)d_in[4];
    const float* w_alpha   = (const float*)d_in[5];
    // d_in[6] (b_alpha) unused: softmax is shift-invariant.
    float* out = (float*)d_out;

    // ws layout: [0, 512K) att_h | [512K, 1M) scores
    char* ws = (char*)d_ws;
    float* att_h  = (float*)(ws);                 // 256*512*4 = 512 KB
    float* scores = (float*)(ws + (512u << 10));  // 256*196*4 = 200 KB

    dim3 g1(kB / 32, kATTH / 32);  // (8,16)
    gemm_atth<<<g1, 256, 0, stream>>>(h, w_h2att, b_h2att, att_h);

    dim3 g2(kB, kChunks);  // (256,4) = 1024 blocks
    scores_kernel<<<g2, 256, 0, stream>>>(p_att, att_h, w_alpha, scores);
    wsum_full<<<kB, 1024, 0, stream>>>(att_feats, scores, out);
}